// Round 22
// baseline (3176.578 us; speedup 1.0000x reference)
//
#include <hip/hip_runtime.h>

typedef __attribute__((ext_vector_type(2))) float f32x2;
typedef __attribute__((ext_vector_type(4))) float f32x4;
typedef __attribute__((ext_vector_type(16))) float f32x16;
typedef __attribute__((ext_vector_type(4))) int i32x4;
typedef __attribute__((ext_vector_type(8))) int i32x8;

// ---------- exact fp8 e4m3fn ENCODE (RNE, saturating), matching ml_dtypes ----------
__device__ __forceinline__ unsigned char enc_e4m3(float y) {
    unsigned int u = __float_as_uint(y);
    unsigned int s = (u >> 31) << 7;
    unsigned int a = u & 0x7fffffffu;
    if (a >= 0x3C800000u) {                       // |y| >= 2^-6: normal e4m3
        unsigned int r = a + 0x7FFFFu + ((a >> 20) & 1u);   // RNE to 3 mant bits
        r &= 0xFFF00000u;
        if (r > 0x43E00000u) r = 0x43E00000u;     // saturate 448
        unsigned int e = (r >> 23) - 120u;
        return (unsigned char)(s | (e << 3) | ((r >> 20) & 7u));
    } else {                                      // subnormal: grid 2^-9
        int m = (int)rintf(__uint_as_float(a) * 512.0f);
        return (unsigned char)(s | (unsigned)m);
    }
}

__device__ __forceinline__ unsigned short f32_to_bf16_bits(float f) {
    unsigned int u = __float_as_uint(f);
    u += 0x7FFFu + ((u >> 16) & 1u);
    return (unsigned short)(u >> 16);
}

// ---------- quantize x: per-row 1x64 tiles -> fp8 (plain row-major) + xsT[t][i] ----------
__global__ __launch_bounds__(256) void quant_x_kernel(const float* __restrict__ x,
                                                      unsigned char* __restrict__ xq,
                                                      float* __restrict__ xsT,
                                                      long long n4, int K, int M) {
    long long g = (long long)blockIdx.x * 256 + threadIdx.x;
    if (g >= n4) return;
    f32x4 v = ((const f32x4*)x)[g];
    float a = fmaxf(fmaxf(fabsf(v.x), fabsf(v.y)), fmaxf(fabsf(v.z), fabsf(v.w)));
    a = fmaxf(a, __shfl_xor(a, 1));
    a = fmaxf(a, __shfl_xor(a, 2));
    a = fmaxf(a, __shfl_xor(a, 4));
    a = fmaxf(a, __shfl_xor(a, 8));
    float scale = fmaxf(a, 1e-12f) / 448.0f;
    long long flat = g * 4;
    uchar4 o;
    o.x = enc_e4m3(v.x / scale);
    o.y = enc_e4m3(v.y / scale);
    o.z = enc_e4m3(v.z / scale);
    o.w = enc_e4m3(v.w / scale);
    *(uchar4*)(xq + flat) = o;
    int row = (int)(flat / K);
    int rem = (int)(flat % K);
    if ((rem & 63) == 0)
        xsT[(size_t)(rem >> 6) * M + row] = scale;
}

// ---------- quantize w: 64x64 blocks -> fp8 (plain) + ws[nb][kb] ----------
__global__ __launch_bounds__(256) void quant_w_kernel(const float* __restrict__ w,
                                                      unsigned char* __restrict__ wq,
                                                      float* __restrict__ ws,
                                                      int N, int K) {
    const int nb = blockIdx.y, kb = blockIdx.x;
    const int KT = K >> 6;
    const int t = threadIdx.x;
    const int rgrp = t >> 4;
    const int cchk = t & 15;
    f32x4 v[4];
    float a = 0.0f;
#pragma unroll
    for (int i = 0; i < 4; ++i) {
        int row = nb * 64 + rgrp + i * 16;
        v[i] = *(const f32x4*)(w + (size_t)row * K + kb * 64 + cchk * 4);
        a = fmaxf(a, fmaxf(fmaxf(fabsf(v[i].x), fabsf(v[i].y)),
                           fmaxf(fabsf(v[i].z), fabsf(v[i].w))));
    }
#pragma unroll
    for (int off = 1; off < 64; off <<= 1) a = fmaxf(a, __shfl_xor(a, off));
    __shared__ float sm[4];
    if ((t & 63) == 0) sm[t >> 6] = a;
    __syncthreads();
    a = fmaxf(fmaxf(sm[0], sm[1]), fmaxf(sm[2], sm[3]));
    float scale = fmaxf(a, 1e-12f) / 448.0f;
#pragma unroll
    for (int i = 0; i < 4; ++i) {
        int row = nb * 64 + rgrp + i * 16;
        uchar4 o;
        o.x = enc_e4m3(v[i].x / scale);
        o.y = enc_e4m3(v[i].y / scale);
        o.z = enc_e4m3(v[i].z / scale);
        o.w = enc_e4m3(v[i].w / scale);
        *(uchar4*)(wq + (size_t)row * K + kb * 64 + cchk * 4) = o;
    }
    if (t == 0) ws[(size_t)nb * KT + kb] = scale;
}

// ---------- 256x256 block-scaled fp8 GEMM, 32x32x64 MFMA, BK=128 macro-tiles ----------
// R18 gate-free core; two 64-K halves per staged buffer -> ONE barrier+vmcnt
// per 128 K-columns.  Half-B frag reads issue after half-A MFMAs (reg reads
// happen at issue -> WAR-safe) and are serviced under the MFMA-A window.
// Scales: global, prefetched one macro-tile ahead, issued BEFORE the GLDS
// batch so compiler waits never drain staging.  LDS layout per half: 64B rows,
// chunk c of row r at slot c ^ ((r>>1)&3).
#define GLDS(srcp, ldsp) __builtin_amdgcn_global_load_lds( \
    (__attribute__((address_space(1))) void*)(srcp),       \
    (__attribute__((address_space(3))) void*)(ldsp), 16, 0, 0)

__global__ __launch_bounds__(512, 2) void gemm_fp8(const unsigned char* __restrict__ Aq,
                                                   const unsigned char* __restrict__ Bq,
                                                   const float* __restrict__ xsT,
                                                   const float* __restrict__ wss,
                                                   const float* __restrict__ bias,
                                                   float* __restrict__ C,
                                                   int M, int N, int K) {
    __shared__ unsigned char Al[2][32768];    // X: 2 macro-bufs x 2 halves x 16KB
    __shared__ unsigned char Bl[2][32768];    // W: same
    const int tid = threadIdx.x;
    const int wid = tid >> 6;
    const int lane = tid & 63;
    const int wm = wid >> 2, wn = wid & 3;    // 2(M) x 4(N), wave-tile 128x64
    const int l31 = lane & 31, h = lane >> 5;
    const int KT = K >> 6;
    const int NT2 = K >> 7;                   // macro-tiles (32)

    // XCD-aware bijective swizzle (nwg = 512, %8==0)
    const int nbx = N >> 8;
    const int nwg = (M >> 8) * nbx;
    const int bid = blockIdx.x;
    const int swz = (bid & 7) * (nwg >> 3) + (bid >> 3);
    const int tm = swz / nbx, tn = swz % nbx;

    const unsigned char* gA = Aq + (size_t)tm * 256 * K;
    const unsigned char* gB = Bq + (size_t)tn * 256 * K;

    const int gswz = (((lane & 3) ^ ((lane >> 3) & 3)) << 4);

    const int fsw = (l31 >> 1) & 3;
    const int slotLo = (2 * h) ^ fsw;
    const int oX = (wm * 128 + l31) * 64;
    const int oW = (wn * 64 + l31) * 64;
    const int oXlo = oX + slotLo * 16, oXhi = oX + (slotLo ^ 1) * 16;
    const int oWlo = oW + slotLo * 16, oWhi = oW + (slotLo ^ 1) * 16;

    const int iRow = tm * 256 + wm * 128 + l31;   // x-row base (mi adds 32)
    const int jbw  = tn * 4 + wn;                 // W 64-block index

    const f32x16 z16 = {0.f,0.f,0.f,0.f,0.f,0.f,0.f,0.f,0.f,0.f,0.f,0.f,0.f,0.f,0.f,0.f};
    f32x16 macc[2][4];                             // [ni][mi]
#pragma unroll
    for (int n = 0; n < 2; ++n)
#pragma unroll
        for (int m = 0; m < 4; ++m) macc[n][m] = z16;

    i32x8 xf[4], wf[2];
    float scl[4];
    float xA0[4], xA1[4], wA0 = 0.f, wA1 = 0.f;   // macro-parity-A scale set
    float xB0[4], xB1[4], wB0 = 0.f, wB1 = 0.f;   // macro-parity-B scale set

    auto STG128 = [&](int T, int bufn) {           // 8 GLDS/wave: full 128-K macro-tile
#pragma unroll
        for (int half = 0; half < 2; ++half) {
#pragma unroll
            for (int i = 0; i < 2; ++i) {
                int seg = wid * 2 + i;
                int row = seg * 16 + (lane >> 2);
                size_t go = (size_t)row * K + (size_t)T * 128 + half * 64 + gswz;
                int db = half * 16384 + seg * 1024;
                GLDS(gA + go, (char*)&Al[bufn][0] + db);
                GLDS(gB + go, (char*)&Bl[bufn][0] + db);
            }
        }
    };

    auto LD_XS = [&](int t64, float (&xs)[4], float& ws) {   // 5 global loads (L2-hot)
#pragma unroll
        for (int m = 0; m < 4; ++m) xs[m] = xsT[(size_t)t64 * M + iRow + m * 32];
        ws = wss[(size_t)jbw * KT + t64];
    };

    auto RD_X = [&](const unsigned char* p, int mi) {
        ((i32x4*)&xf[mi])[0] = *(const i32x4*)(p + oXlo + mi * 2048);
        ((i32x4*)&xf[mi])[1] = *(const i32x4*)(p + oXhi + mi * 2048);
    };
    auto RD_W = [&](const unsigned char* p, int ni) {
        ((i32x4*)&wf[ni])[0] = *(const i32x4*)(p + oWlo + ni * 2048);
        ((i32x4*)&wf[ni])[1] = *(const i32x4*)(p + oWhi + ni * 2048);
    };
    auto RD_ALL = [&](const unsigned char* pXp, const unsigned char* pWp) {
        RD_W(pWp, 0); RD_W(pWp, 1);
        RD_X(pXp, 0); RD_X(pXp, 1); RD_X(pXp, 2); RD_X(pXp, 3);
    };

    auto RESC = [&](f32x16& acc, const f32x16& p, float s) {   // 8 x v_pk_fma_f32
        f32x2 sv = {s, s};
#pragma unroll
        for (int k = 0; k < 8; ++k) {
            f32x2 a = {acc[2 * k], acc[2 * k + 1]};
            f32x2 q = {p[2 * k], p[2 * k + 1]};
            a = __builtin_elementwise_fma(q, sv, a);
            acc[2 * k] = a.x;
            acc[2 * k + 1] = a.y;
        }
    };

    auto CL = [&](int ni, int mi0) {
#pragma unroll
        for (int q = 0; q < 2; ++q) {
            const int mi = mi0 + q;
            f32x16 p = __builtin_amdgcn_mfma_scale_f32_32x32x64_f8f6f4(
                wf[ni], xf[mi], z16, 0, 0, 0, 0x7F7F7F7F, 0, 0x7F7F7F7F);
            RESC(macc[ni][mi], p, scl[mi]);
        }
    };

    // one macro-tile (128 K-cols): cur = this tile's scale set, nxt refilled for T+1
    auto BODY = [&](int T, int buf,
                    float (&cx0)[4], float& cw0, float (&cx1)[4], float& cw1,
                    float (&nx0)[4], float& nw0, float (&nx1)[4], float& nw1) {
        int t1 = T + 1; if (t1 == NT2) t1 = 0;     // wrap (redundant but uniform)
        const unsigned char* pXa = &Al[buf][0];
        const unsigned char* pWa = &Bl[buf][0];
        const unsigned char* pXb = pXa + 16384;
        const unsigned char* pWb = pWa + 16384;
        const unsigned char* pXn = &Al[buf ^ 1][0];
        const unsigned char* pWn = &Bl[buf ^ 1][0];

        // next macro-tile's scales FIRST (so compiler waits don't drain staging)
        LD_XS(2 * t1, nx0, nw0);
        LD_XS(2 * t1 + 1, nx1, nw1);
        STG128(t1, buf ^ 1);                       // 8 GLDS

#pragma unroll
        for (int m = 0; m < 4; ++m) scl[m] = cx0[m] * cw0;

        // ---- half A (frags tail-read last macro-tile) ----
        asm volatile("s_waitcnt lgkmcnt(0)" ::: "memory");
        __builtin_amdgcn_sched_barrier(0);
        __builtin_amdgcn_s_setprio(1); CL(0, 0); __builtin_amdgcn_s_setprio(0);
        __builtin_amdgcn_s_setprio(1); CL(1, 0); __builtin_amdgcn_s_setprio(0);
        __builtin_amdgcn_s_setprio(1); CL(0, 2); __builtin_amdgcn_s_setprio(0);
        __builtin_amdgcn_s_setprio(1); CL(1, 2); __builtin_amdgcn_s_setprio(0);

        // ---- half B: reads issue after half-A MFMAs issued (WAR-safe) ----
        RD_ALL(pXb, pWb);
#pragma unroll
        for (int m = 0; m < 4; ++m) scl[m] = cx1[m] * cw1;
        asm volatile("s_waitcnt lgkmcnt(0)" ::: "memory");
        __builtin_amdgcn_sched_barrier(0);
        __builtin_amdgcn_s_setprio(1); CL(0, 0); __builtin_amdgcn_s_setprio(0);
        __builtin_amdgcn_s_setprio(1); CL(1, 0); __builtin_amdgcn_s_setprio(0);
        __builtin_amdgcn_s_setprio(1); CL(0, 2); __builtin_amdgcn_s_setprio(0);
        __builtin_amdgcn_s_setprio(1); CL(1, 2); __builtin_amdgcn_s_setprio(0);

        // ---- macro-tile boundary: ONE vmcnt + barrier per 128 K-cols ----
        asm volatile("s_waitcnt vmcnt(0)" ::: "memory");
        asm volatile("s_barrier" ::: "memory");
        RD_ALL(pXn, pWn);                          // tail: next macro-tile half A
    };

    // ---- prologue ----
    LD_XS(0, xA0, wA0);
    LD_XS(1, xA1, wA1);
    STG128(0, 0);
    asm volatile("s_waitcnt vmcnt(0)" ::: "memory");
    asm volatile("s_barrier" ::: "memory");
    RD_ALL(&Al[0][0], &Bl[0][0]);                  // half A of macro-tile 0

    for (int T = 0; T < NT2; T += 2) {
        BODY(T,     0, xA0, wA0, xA1, wA1, xB0, wB0, xB1, wB1);
        BODY(T + 1, 1, xB0, wB0, xB1, wB1, xA0, wA0, xA1, wA1);
    }

    // epilogue: D col = lane&31 -> x-row i; D row = (reg&3)+8*(reg>>2)+4h -> w-col j
    const int i0 = tm * 256 + wm * 128 + l31;
    const int jn = tn * 256 + wn * 64 + 4 * h;
#pragma unroll
    for (int ni = 0; ni < 2; ++ni) {
#pragma unroll
        for (int mi = 0; mi < 4; ++mi) {
            const int row = i0 + mi * 32;
#pragma unroll
            for (int q = 0; q < 4; ++q) {
                const int col = jn + ni * 32 + 8 * q;
                f32x4 bv = *(const f32x4*)(bias + col);
                f32x4 vo;
#pragma unroll
                for (int j = 0; j < 4; ++j) {
                    unsigned short b = f32_to_bf16_bits(macc[ni][mi][q * 4 + j]);
                    vo[j] = __uint_as_float(((unsigned int)b) << 16) + bv[j];
                }
                *(f32x4*)(C + (size_t)row * N + col) = vo;
            }
        }
    }
}

extern "C" void kernel_launch(void* const* d_in, const int* in_sizes, int n_in,
                              void* d_out, int out_size, void* d_ws, size_t ws_size,
                              hipStream_t stream) {
    const float* x    = (const float*)d_in[0];
    const float* w    = (const float*)d_in[1];
    const float* bias = (const float*)d_in[2];
    float* out = (float*)d_out;

    const int N = in_sizes[2];
    const long long KL = (long long)in_sizes[1] / N;
    const int K = (int)KL;
    const int M = (int)((long long)in_sizes[0] / KL);
    const int KT = K / 64;

    unsigned char* xq = (unsigned char*)d_ws;                       // M*K fp8
    unsigned char* wq = xq + (size_t)M * K;                         // N*K fp8
    float* xsT = (float*)(wq + (size_t)N * K);                      // KT*M f32
    float* wss = xsT + (size_t)KT * M;                              // (N/64)*KT f32

    long long n4 = (long long)M * K / 4;
    quant_x_kernel<<<(unsigned)((n4 + 255) / 256), 256, 0, stream>>>(x, xq, xsT, n4, K, M);

    dim3 gw(K / 64, N / 64);
    quant_w_kernel<<<gw, 256, 0, stream>>>(w, wq, wss, N, K);

    const int nwg = (M / 256) * (N / 256);
    gemm_fp8<<<nwg, 512, 0, stream>>>(xq, wq, xsT, wss, bias, out, M, N, K);
}

// Round 23
// 255.538 us; speedup vs baseline: 12.4309x; 12.4309x over previous
//
#include <hip/hip_runtime.h>

typedef __attribute__((ext_vector_type(2))) float f32x2;
typedef __attribute__((ext_vector_type(4))) float f32x4;
typedef __attribute__((ext_vector_type(16))) float f32x16;
typedef __attribute__((ext_vector_type(4))) int i32x4;
typedef __attribute__((ext_vector_type(8))) int i32x8;

// ---------- exact fp8 e4m3fn ENCODE (RNE, saturating), matching ml_dtypes ----------
__device__ __forceinline__ unsigned char enc_e4m3(float y) {
    unsigned int u = __float_as_uint(y);
    unsigned int s = (u >> 31) << 7;
    unsigned int a = u & 0x7fffffffu;
    if (a >= 0x3C800000u) {                       // |y| >= 2^-6: normal e4m3
        unsigned int r = a + 0x7FFFFu + ((a >> 20) & 1u);   // RNE to 3 mant bits
        r &= 0xFFF00000u;
        if (r > 0x43E00000u) r = 0x43E00000u;     // saturate 448
        unsigned int e = (r >> 23) - 120u;
        return (unsigned char)(s | (e << 3) | ((r >> 20) & 7u));
    } else {                                      // subnormal: grid 2^-9
        int m = (int)rintf(__uint_as_float(a) * 512.0f);
        return (unsigned char)(s | (unsigned)m);
    }
}

__device__ __forceinline__ unsigned short f32_to_bf16_bits(float f) {
    unsigned int u = __float_as_uint(f);
    u += 0x7FFFu + ((u >> 16) & 1u);
    return (unsigned short)(u >> 16);
}

// ---------- quantize x: per-row 1x64 tiles -> fp8 (plain row-major) + xsT[t][i] ----------
__global__ __launch_bounds__(256) void quant_x_kernel(const float* __restrict__ x,
                                                      unsigned char* __restrict__ xq,
                                                      float* __restrict__ xsT,
                                                      long long n4, int K, int M) {
    long long g = (long long)blockIdx.x * 256 + threadIdx.x;
    if (g >= n4) return;
    f32x4 v = ((const f32x4*)x)[g];
    float a = fmaxf(fmaxf(fabsf(v.x), fabsf(v.y)), fmaxf(fabsf(v.z), fabsf(v.w)));
    a = fmaxf(a, __shfl_xor(a, 1));
    a = fmaxf(a, __shfl_xor(a, 2));
    a = fmaxf(a, __shfl_xor(a, 4));
    a = fmaxf(a, __shfl_xor(a, 8));
    float scale = fmaxf(a, 1e-12f) / 448.0f;
    long long flat = g * 4;
    uchar4 o;
    o.x = enc_e4m3(v.x / scale);
    o.y = enc_e4m3(v.y / scale);
    o.z = enc_e4m3(v.z / scale);
    o.w = enc_e4m3(v.w / scale);
    *(uchar4*)(xq + flat) = o;
    int row = (int)(flat / K);
    int rem = (int)(flat % K);
    if ((rem & 63) == 0)
        xsT[(size_t)(rem >> 6) * M + row] = scale;
}

// ---------- quantize w: 64x64 blocks -> fp8 (plain) + ws[nb][kb] ----------
__global__ __launch_bounds__(256) void quant_w_kernel(const float* __restrict__ w,
                                                      unsigned char* __restrict__ wq,
                                                      float* __restrict__ ws,
                                                      int N, int K) {
    const int nb = blockIdx.y, kb = blockIdx.x;
    const int KT = K >> 6;
    const int t = threadIdx.x;
    const int rgrp = t >> 4;
    const int cchk = t & 15;
    f32x4 v[4];
    float a = 0.0f;
#pragma unroll
    for (int i = 0; i < 4; ++i) {
        int row = nb * 64 + rgrp + i * 16;
        v[i] = *(const f32x4*)(w + (size_t)row * K + kb * 64 + cchk * 4);
        a = fmaxf(a, fmaxf(fmaxf(fabsf(v[i].x), fabsf(v[i].y)),
                           fmaxf(fabsf(v[i].z), fabsf(v[i].w))));
    }
#pragma unroll
    for (int off = 1; off < 64; off <<= 1) a = fmaxf(a, __shfl_xor(a, off));
    __shared__ float sm[4];
    if ((t & 63) == 0) sm[t >> 6] = a;
    __syncthreads();
    a = fmaxf(fmaxf(sm[0], sm[1]), fmaxf(sm[2], sm[3]));
    float scale = fmaxf(a, 1e-12f) / 448.0f;
#pragma unroll
    for (int i = 0; i < 4; ++i) {
        int row = nb * 64 + rgrp + i * 16;
        uchar4 o;
        o.x = enc_e4m3(v[i].x / scale);
        o.y = enc_e4m3(v[i].y / scale);
        o.z = enc_e4m3(v[i].z / scale);
        o.w = enc_e4m3(v[i].w / scale);
        *(uchar4*)(wq + (size_t)row * K + kb * 64 + cchk * 4) = o;
    }
    if (t == 0) ws[(size_t)nb * KT + kb] = scale;
}

// ---------- 256x256 block-scaled fp8 GEMM, 32x32x64 MFMA, gate-free tiles ----------
// R18 (verified best: 215us gemm, 257.9us total).  All 17 LDS reads of a tile
// (5 scales + 12 frags) issued in the post-barrier tail; ONE lgkmcnt(0) per
// tile, then 8 uninterrupted MFMA+rescale clusters.  No intra-tile LDS gates
// -> the 2 waves/SIMD co-schedule.  LDS layout: 64B rows, chunk c of row r at
// slot c ^ ((r>>1)&3).
// NOTE (R19/R20/R22 post-mortems): at this tile size the register file has
// ~12 spare regs; any schedule extending fragment/scale liveness across a
// phase boundary spills macc (128 AGPR) to scratch at 15x cost.  Do not add
// cross-tile prefetch state.
#define GLDS(srcp, ldsp) __builtin_amdgcn_global_load_lds( \
    (__attribute__((address_space(1))) void*)(srcp),       \
    (__attribute__((address_space(3))) void*)(ldsp), 16, 0, 0)

__global__ __launch_bounds__(512, 2) void gemm_fp8(const unsigned char* __restrict__ Aq,
                                                   const unsigned char* __restrict__ Bq,
                                                   const float* __restrict__ xsT,
                                                   const float* __restrict__ wss,
                                                   const float* __restrict__ bias,
                                                   float* __restrict__ C,
                                                   int M, int N, int K) {
    __shared__ unsigned char Al[32768];       // X: 2 bufs x (256 rows x 64B)
    __shared__ unsigned char Bl[32768];       // W: same
    __shared__ float xs_l[64 * 256];          // 64 KB: xs, all K-tiles (KT<=64)
    __shared__ float ws_l[4 * 64];            // 1 KB: ws for the 4 W 64-blocks
    const int tid = threadIdx.x;
    const int wid = tid >> 6;
    const int lane = tid & 63;
    const int wm = wid >> 2, wn = wid & 3;    // 2(M) x 4(N), wave-tile 128x64
    const int l31 = lane & 31, h = lane >> 5;
    const int KT = K >> 6, NT = KT;

    // XCD-aware bijective swizzle (nwg = 512, %8==0)
    const int nbx = N >> 8;
    const int nwg = (M >> 8) * nbx;
    const int bid = blockIdx.x;
    const int swz = (bid & 7) * (nwg >> 3) + (bid >> 3);
    const int tm = swz / nbx, tn = swz % nbx;

    const unsigned char* gA = Aq + (size_t)tm * 256 * K;
    const unsigned char* gB = Bq + (size_t)tn * 256 * K;

    const int gswz = (((lane & 3) ^ ((lane >> 3) & 3)) << 4);

    const int fsw = (l31 >> 1) & 3;
    const int slotLo = (2 * h) ^ fsw;
    const int oX = (wm * 128 + l31) * 64;
    const int oW = (wn * 64 + l31) * 64;
    const int oXlo = oX + slotLo * 16, oXhi = oX + (slotLo ^ 1) * 16;
    const int oWlo = oW + slotLo * 16, oWhi = oW + (slotLo ^ 1) * 16;

    const int xsoff = wm * 128 + l31;             // local x-row (mi adds 32)

    const f32x16 z16 = {0.f,0.f,0.f,0.f,0.f,0.f,0.f,0.f,0.f,0.f,0.f,0.f,0.f,0.f,0.f,0.f};
    f32x16 macc[2][4];                             // [ni][mi]
#pragma unroll
    for (int n = 0; n < 2; ++n)
#pragma unroll
        for (int m = 0; m < 4; ++m) macc[n][m] = z16;

    i32x8 xf[4], wf[2];
    float xsr[4], wsr = 0.f, scl[4];

    auto STG = [&](int t64, int bufn) {            // 4 GLDS/wave
#pragma unroll
        for (int i = 0; i < 2; ++i) {
            int seg = wid * 2 + i;
            int row = seg * 16 + (lane >> 2);
            size_t go = (size_t)row * K + (size_t)t64 * 64 + gswz;
            GLDS(gA + go, (char*)Al + bufn * 16384 + seg * 1024);
            GLDS(gB + go, (char*)Bl + bufn * 16384 + seg * 1024);
        }
    };

    auto RD_S = [&](int t) {                       // 5 ds_read_b32 (issue FIRST in tail)
#pragma unroll
        for (int m = 0; m < 4; ++m) xsr[m] = xs_l[t * 256 + xsoff + m * 32];
        wsr = ws_l[wn * KT + t];
    };

    auto RD_X = [&](const unsigned char* p, int mi) {
        ((i32x4*)&xf[mi])[0] = *(const i32x4*)(p + oXlo + mi * 2048);
        ((i32x4*)&xf[mi])[1] = *(const i32x4*)(p + oXhi + mi * 2048);
    };
    auto RD_W = [&](const unsigned char* p, int ni) {
        ((i32x4*)&wf[ni])[0] = *(const i32x4*)(p + oWlo + ni * 2048);
        ((i32x4*)&wf[ni])[1] = *(const i32x4*)(p + oWhi + ni * 2048);
    };

    auto RD_ALL = [&](const unsigned char* pXp, const unsigned char* pWp) {
        RD_W(pWp, 0); RD_W(pWp, 1);
        RD_X(pXp, 0); RD_X(pXp, 1); RD_X(pXp, 2); RD_X(pXp, 3);
    };

    // packed rescale: 8 x v_pk_fma_f32
    auto RESC = [&](f32x16& acc, const f32x16& p, float s) {
        f32x2 sv = {s, s};
#pragma unroll
        for (int k = 0; k < 8; ++k) {
            f32x2 a = {acc[2 * k], acc[2 * k + 1]};
            f32x2 q = {p[2 * k], p[2 * k + 1]};
            a = __builtin_elementwise_fma(q, sv, a);
            acc[2 * k] = a.x;
            acc[2 * k + 1] = a.y;
        }
    };

    auto CL = [&](int ni, int mi0) {
#pragma unroll
        for (int q = 0; q < 2; ++q) {
            const int mi = mi0 + q;
            f32x16 p = __builtin_amdgcn_mfma_scale_f32_32x32x64_f8f6f4(
                wf[ni], xf[mi], z16, 0, 0, 0, 0x7F7F7F7F, 0, 0x7F7F7F7F);
            RESC(macc[ni][mi], p, scl[mi]);
        }
    };

    // ---- prologue: fill scale LDS (coalesced), stage tile 0, sync ----
    const int xtot = KT * 256;
    for (int idx = tid; idx < xtot; idx += 512)
        xs_l[idx] = xsT[(size_t)(idx >> 8) * M + tm * 256 + (idx & 255)];
    for (int idx = tid; idx < 4 * KT; idx += 512)
        ws_l[idx] = wss[(size_t)(tn * 4 + idx / KT) * KT + (idx % KT)];
    STG(0, 0);
    __syncthreads();
    RD_S(0);
    RD_ALL(Al, Bl);                                // all 17 reads for tile 0

    for (int t = 0; t < NT; ++t) {
        const int buf = t & 1;
        const unsigned char* pXn = Al + (buf ^ 1) * 16384;
        const unsigned char* pWn = Bl + (buf ^ 1) * 16384;
        int t1 = t + 1; if (t1 == NT) t1 = 0;      // wrap (redundant last stage)

        STG(t1, buf ^ 1);                          // stage next tile (vmcnt)

#pragma unroll
        for (int m = 0; m < 4; ++m) scl[m] = xsr[m] * wsr;

        // ONE wait for all 12 frag reads, then uninterrupted MFMA phase
        asm volatile("s_waitcnt lgkmcnt(0)" ::: "memory");
        __builtin_amdgcn_sched_barrier(0);
        __builtin_amdgcn_s_setprio(1); CL(0, 0); __builtin_amdgcn_s_setprio(0);
        __builtin_amdgcn_s_setprio(1); CL(1, 0); __builtin_amdgcn_s_setprio(0);
        __builtin_amdgcn_s_setprio(1); CL(0, 2); __builtin_amdgcn_s_setprio(0);
        __builtin_amdgcn_s_setprio(1); CL(1, 2); __builtin_amdgcn_s_setprio(0);

        // tile boundary + full tail-read of next tile (17 LDS reads, no gate)
        asm volatile("s_waitcnt vmcnt(0)" ::: "memory");
        asm volatile("s_barrier" ::: "memory");
        RD_S(t1);
        RD_ALL(pXn, pWn);
    }

    // epilogue: D col = lane&31 -> x-row i; D row = (reg&3)+8*(reg>>2)+4h -> w-col j
    const int i0 = tm * 256 + wm * 128 + l31;
    const int jn = tn * 256 + wn * 64 + 4 * h;
#pragma unroll
    for (int ni = 0; ni < 2; ++ni) {
#pragma unroll
        for (int mi = 0; mi < 4; ++mi) {
            const int row = i0 + mi * 32;
#pragma unroll
            for (int q = 0; q < 4; ++q) {
                const int col = jn + ni * 32 + 8 * q;
                f32x4 bv = *(const f32x4*)(bias + col);
                f32x4 vo;
#pragma unroll
                for (int j = 0; j < 4; ++j) {
                    unsigned short b = f32_to_bf16_bits(macc[ni][mi][q * 4 + j]);
                    vo[j] = __uint_as_float(((unsigned int)b) << 16) + bv[j];
                }
                *(f32x4*)(C + (size_t)row * N + col) = vo;
            }
        }
    }
}

extern "C" void kernel_launch(void* const* d_in, const int* in_sizes, int n_in,
                              void* d_out, int out_size, void* d_ws, size_t ws_size,
                              hipStream_t stream) {
    const float* x    = (const float*)d_in[0];
    const float* w    = (const float*)d_in[1];
    const float* bias = (const float*)d_in[2];
    float* out = (float*)d_out;

    const int N = in_sizes[2];
    const long long KL = (long long)in_sizes[1] / N;
    const int K = (int)KL;
    const int M = (int)((long long)in_sizes[0] / KL);
    const int KT = K / 64;

    unsigned char* xq = (unsigned char*)d_ws;                       // M*K fp8
    unsigned char* wq = xq + (size_t)M * K;                         // N*K fp8
    float* xsT = (float*)(wq + (size_t)N * K);                      // KT*M f32
    float* wss = xsT + (size_t)KT * M;                              // (N/64)*KT f32

    long long n4 = (long long)M * K / 4;
    quant_x_kernel<<<(unsigned)((n4 + 255) / 256), 256, 0, stream>>>(x, xq, xsT, n4, K, M);

    dim3 gw(K / 64, N / 64);
    quant_w_kernel<<<gw, 256, 0, stream>>>(w, wq, wss, N, K);

    const int nwg = (M / 256) * (N / 256);
    gemm_fp8<<<nwg, 512, 0, stream>>>(xq, wq, xsT, wss, bias, out, M, N, K);
}